// Round 7
// baseline (120.512 us; speedup 1.0000x reference)
//
#include <hip/hip_runtime.h>
#include <math.h>

// Problem constants (B=4, N=2048, C=81)
#define NPROP 2048
#define NIMG 4
#define NCLS 81
#define REGW 648          // C*8
#define SCORE_THRESH 0.05f
#define NMS_T 0.5f
#define DETS 100
#define XC 1023.0f        // IMG_W - 1
#define YC 799.0f         // IMG_H - 1
#define BBOX_CLIP 4.135166556742356f  // log(1000/16)
#define NBIN 8192         // 13-bit score-bin histogram (v >> 19)
#define SEL 320           // tranche target (coarse bin crossing; C1 lands ~500)
#define MAXC 512          // fast-path candidate cap
#define WRD 8             // MAXC/64 keep words
#define TRIP 2560         // padded triangular words: 64*(9+7+7+5+5+3+3+1)

typedef unsigned long long u64;

__device__ __forceinline__ float areaf(float4 v) {
  return fmaxf(v.z - v.x + 1.0f, 0.0f) * fmaxf(v.w - v.y + 1.0f, 0.0f);
}
__device__ __forceinline__ bool iou_gt(float4 a, float aa, float4 b, float ba) {
  float ix1 = fmaxf(a.x, b.x), iy1 = fmaxf(a.y, b.y);
  float ix2 = fminf(a.z, b.z), iy2 = fminf(a.w, b.w);
  float iw = fmaxf(ix2 - ix1 + 1.0f, 0.0f);
  float ih = fmaxf(iy2 - iy1 + 1.0f, 0.0f);
  float inter = iw * ih;
  return inter > NMS_T * fmaxf(aa + ba - inter, 1e-6f);
}
__device__ __forceinline__ float score_from_v(unsigned v) {
  unsigned uu = ~v;
  unsigned bits = (uu & 0x80000000u) ? (uu & 0x7fffffffu) : ~uu;
  return __uint_as_float(bits);
}
// decode arithmetic from already-loaded regression float4 + proposal float4
__device__ __forceinline__ float4 decode_math(float4 rr, float4 P) {
  float w  = P.z - P.x + 1.0f;
  float h  = P.w - P.y + 1.0f;
  float cx = P.x + 0.5f * w;
  float cy = P.y + 0.5f * h;
  float dx = rr.x / 10.0f;
  float dy = rr.y / 10.0f;
  float dw = fminf(rr.z / 5.0f, BBOX_CLIP);
  float dh = fminf(rr.w / 5.0f, BBOX_CLIP);
  float pcx = dx * w + cx;
  float pcy = dy * h + cy;
  float pw = expf(dw) * w;
  float ph = expf(dh) * h;
  float4 o;
  o.x = fminf(fmaxf(pcx - 0.5f * pw, 0.0f), XC);
  o.y = fminf(fmaxf(pcy - 0.5f * ph, 0.0f), YC);
  o.z = fminf(fmaxf(pcx + 0.5f * pw - 1.0f, 0.0f), XC);
  o.w = fminf(fmaxf(pcy + 0.5f * ph - 1.0f, 0.0f), YC);
  return o;
}
__device__ __forceinline__ float4 decode_side(const float* __restrict__ reg,
                                              const float4* __restrict__ props,
                                              int grow, int ci, int isR) {
  const float4 rr = *(const float4*)(reg + (size_t)grow * REGW + ci * 8 + isR * 4);
  return decode_math(rr, props[grow]);
}

// ---------------------------------------------------------------------------
// K1: wide per-row softmax-argmax -> v32 + ci16; first 72 blocks also zero out;
// block 0 resets the cross-block handshake flags (re-poison safety).
// ---------------------------------------------------------------------------
__global__ __launch_bounds__(256) void score_kernel(
    const float* __restrict__ logits,
    unsigned* __restrict__ v32G, unsigned short* __restrict__ ci16G,
    int* __restrict__ doneG, float* __restrict__ out) {
  int row  = blockIdx.x * 4 + (threadIdx.x >> 6);
  int lane = threadIdx.x & 63;
  if (blockIdx.x == 0 && threadIdx.x < NIMG) doneG[threadIdx.x] = 0;
  if (blockIdx.x < 72) {                // zero output: 72*256 = 18432 float4s
    int g = blockIdx.x * 256 + threadIdx.x;
    ((float4*)out)[g] = make_float4(0.f, 0.f, 0.f, 0.f);
  }
  const float* lr = logits + (size_t)row * NCLS;
  float a = lr[lane];
  float b = (lane < NCLS - 64) ? lr[lane + 64] : -INFINITY;
  float v; int ci;
  if (b > a) { v = b; ci = lane + 64; } else { v = a; ci = lane; }
  for (int o = 32; o; o >>= 1) {        // wave argmax, min-index ties
    float ov = __shfl_xor(v, o);
    int   oc = __shfl_xor(ci, o);
    if (ov > v || (ov == v && oc < ci)) { v = ov; ci = oc; }
  }
  float e = expf(a - v) + ((lane < NCLS - 64) ? expf(b - v) : 0.0f);
  for (int o = 32; o; o >>= 1) e += __shfl_xor(e, o);
  if (lane == 0) {
    float score = 1.0f / e;             // softmax at argmax (numerator exp(0))
    unsigned vv = 0xFFFFFFFFu;
    if (ci >= 1 && score > SCORE_THRESH) {
      unsigned uu = __float_as_uint(score);
      uu = (uu & 0x80000000u) ? ~uu : (uu | 0x80000000u);
      vv = ~uu;                         // ascending vv == descending score
    }
    v32G[row]  = vv;
    ci16G[row] = (unsigned short)ci;
  }
}

// ---- phase-2 shared layout (~69 KB) ----
struct P2S {
  int hist[NBIN];              // 32 KB
  u64 keys[MAXC];              // 4 KB   key = v<<32 | p<<21 | ci<<14
  unsigned short ssort[MAXC];  // 1 KB   sorted pos -> row
  unsigned svs[MAXC];          // 2 KB   sorted pos -> v32
  float4 bx[MAXC];             // 8 KB   sorted decoded boxes
  u64 mat[TRIP];               // 20 KB  triangular bit matrix
  int rnk[MAXC];               // 2 KB   unsorted slot -> rank
  int wsum[16];
  int Ts, cnts, ovf;
};

// ---- fallback shared layout (~53 KB), overlaid on P2S ----
struct SN {
  u64 keys[NPROP];
  unsigned short sidx[NPROP];
  unsigned v32s[NPROP];
  float4 bxL[MAXC], bxR[MAXC];
  float  arL[MAXC], arR[MAXC];
  u64 keepbL[NPROP / 64], keepbR[NPROP / 64];
  u64 rowmL[64], rowmR[64];
  float4 cbL[64], cbR[64];
  float  cbLa[64], cbRa[64];
  u64 aL, aR;
  int cnt, prevCount, done, ccL, ccR, needFB;
  unsigned kthV;
};

__device__ __forceinline__ float4 get_sboxN(SN* S, const float* reg,
                                            const float4* lp4, const float4* rp4,
                                            const unsigned short* ci16G,
                                            int b, int pos, int isR) {
  if (pos < MAXC) return isR ? S->bxR[pos] : S->bxL[pos];
  int row = S->sidx[pos];
  int grow = b * NPROP + row;
  return decode_side(reg, isR ? rp4 : lp4, grow, ci16G[grow], isR);
}

// ---------------------------------------------------------------------------
// K2' (8 blocks = image x side, 1024 thr): select + decode(overlapped with
// rank-sort) + ballot-matrix + greedy; side-1 publishes keepR via agent-scope
// release; side-0 runs finale + dormant exact fallback.
// R7: latency-chain fixes — batch-8 register-staged sort loads (keys padded
// to x8 with ~0ull sentinels), greedy off-diag row segments hoisted to regs.
// ---------------------------------------------------------------------------
__global__ __launch_bounds__(1024) void nms_fused_kernel(
    const unsigned* __restrict__ v32G, const unsigned short* __restrict__ ci16G,
    const float* __restrict__ reg, const float* __restrict__ lp,
    const float* __restrict__ rp,
    float4* __restrict__ bxRG, u64* __restrict__ keepRG,
    int* __restrict__ doneG, float* __restrict__ out) {
  constexpr unsigned SMEM = (sizeof(P2S) > sizeof(SN)) ? sizeof(P2S) : sizeof(SN);
  __shared__ __align__(16) char smemRaw[SMEM];
  P2S& P = *reinterpret_cast<P2S*>(smemRaw);
  SN&  S = *reinterpret_cast<SN*>(smemRaw);

  int b = blockIdx.x >> 1, side = blockIdx.x & 1;
  int tid = threadIdx.x, ln = tid & 63, w = tid >> 6;
  const unsigned* v32 = v32G + b * NPROP;
  const unsigned short* ci16 = ci16G + b * NPROP;

  // ---- select: hist threshold (loads prefetched over LDS zeroing) ----
  unsigned vA0 = v32[tid], vA1 = v32[tid + 1024];
  unsigned cA0 = ci16[tid], cA1 = ci16[tid + 1024];
  if (tid == 0) { P.Ts = NBIN - 1; P.cnts = 0; P.ovf = 0; }
  for (int i = tid; i < NBIN / 4; i += 1024)
    ((int4*)P.hist)[i] = make_int4(0, 0, 0, 0);
  __syncthreads();
  if (vA0 != 0xFFFFFFFFu) atomicAdd(&P.hist[vA0 >> 19], 1);
  if (vA1 != 0xFFFFFFFFu) atomicAdd(&P.hist[vA1 >> 19], 1);
  __syncthreads();
  {  // scan 8192 bins (8/thread) -> threshold bin Ts (cum >= SEL), total
    int base = tid * 8;
    int c[8]; int acc = 0;
#pragma unroll
    for (int k = 0; k < 8; ++k) { acc += P.hist[base + k]; c[k] = acc; }
    int tot = acc, v = tot;
#pragma unroll
    for (int o = 1; o < 64; o <<= 1) { int n = __shfl_up(v, o); if (ln >= o) v += n; }
    if (ln == 63) P.wsum[w] = v;
    __syncthreads();
    if (tid < 16) {
      int x = P.wsum[tid];
#pragma unroll
      for (int o = 1; o < 16; o <<= 1) { int n = __shfl_up(x, o); if (tid >= o) x += n; }
      P.wsum[tid] = x;
    }
    __syncthreads();
    int incl = ((w > 0) ? P.wsum[w - 1] : 0) + v;
    int off = incl - tot;
    int prev = off;
#pragma unroll
    for (int k = 0; k < 8; ++k) {
      int cur = off + c[k];
      if (cur >= SEL && prev < SEL) P.Ts = base + k;
      prev = cur;
    }
  }
  __syncthreads();
  int T = P.Ts, nvTot = P.wsum[15];
  {  // compact bin <= T (cached regs; key carries ci below p: order = (v,p))
    unsigned vv[2] = {vA0, vA1};
    unsigned cc[2] = {cA0, cA1};
#pragma unroll
    for (int it = 0; it < 2; ++it) {
      int p = tid + it * 1024;
      unsigned v = vv[it];
      bool cand = (v != 0xFFFFFFFFu) && ((int)(v >> 19) <= T);
      u64 mb = __ballot(cand);
      int lpos = (int)__popcll(mb & ((1ull << ln) - 1ull));
      int wb = 0;
      if (ln == 0 && mb) wb = atomicAdd(&P.cnts, (int)__popcll(mb));
      wb = __shfl(wb, 0);
      if (cand) {
        int dst = wb + lpos;
        if (dst < MAXC)
          P.keys[dst] = ((u64)v << 32) | ((u64)p << 21) | ((u64)cc[it] << 14);
        else P.ovf = 1;
      }
    }
  }
  __syncthreads();
  int C1 = P.cnts;
  bool skipSel = (C1 > MAXC) || P.ovf;   // block-uniform
  u64 A[WRD];                            // greedy result (wave 0 only)

  if (!skipSel) {
    int C1r = (C1 + 7) & ~7;             // pad keys to x8 (C1r <= MAXC)
    if (tid >= C1 && tid < C1r) P.keys[tid] = ~0ull;   // sentinel > all keys
    __syncthreads();
    // ---- decode loads issued EARLY (unsorted slot tid), overlap rank-sort ----
    float4 rrD, ppD;
    unsigned myv = 0; int myp = 0;
    bool hasKey = (tid < C1);
    if (hasKey) {
      u64 k = P.keys[tid];
      myv = (unsigned)(k >> 32);
      myp = (int)((k >> 21) & 0x7FF);
      int myci = (int)((k >> 14) & 0x7F);
      int grow = b * NPROP + myp;
      ppD = ((const float4*)(side ? rp : lp))[grow];
      rrD = *(const float4*)(reg + (size_t)grow * REGW + myci * 8 + side * 4);
    }
    // ---- rank-sort: 4 waves, 2 keys/thread; batch-8 register-staged loads
    //      (8 LDS loads in flight per iter -> latency amortized 8x) ----
    if (tid < 256) {
      int i0 = tid, i1 = tid + 256;
      u64 k0 = (i0 < C1) ? P.keys[i0] : ~0ull;
      u64 k1 = (i1 < C1) ? P.keys[i1] : ~0ull;
      int r0 = 0, r1 = 0;
#pragma unroll 2
      for (int j0 = 0; j0 < C1r; j0 += 8) {
        u64 kb[8];
#pragma unroll
        for (int t = 0; t < 8; ++t) kb[t] = P.keys[j0 + t];
#pragma unroll
        for (int t = 0; t < 8; ++t) {
          r0 += (kb[t] < k0) ? 1 : 0;
          r1 += (kb[t] < k1) ? 1 : 0;
        }
      }
      if (i0 < C1) P.rnk[i0] = r0;
      if (i1 < C1) P.rnk[i1] = r1;
    }
    __syncthreads();
    // ---- decode compute + scatter to sorted position ----
    if (hasKey) {
      int R = P.rnk[tid];
      float4 B = decode_math(rrD, ppD);
      P.bx[R] = B;
      P.ssort[R] = (unsigned short)myp;
      P.svs[R] = myv;
      if (side) bxRG[b * MAXC + R] = B;   // side-1 publishes boxes for finale
    }
    if (tid >= C1 && tid < MAXC) P.bx[tid] = make_float4(0.f, 0.f, 0.f, 0.f);
    __syncthreads();

    // ---- matrix build: register-held columns + row-broadcast ballot ----
    int WRDu = (C1 + 63) >> 6;
    {
      int rb = w & 7, part = w >> 3;
      int K = WRDu - rb;
      if (K > 0 && rb * 64 < C1) {
        float4 cbx[8]; float car[8];
#pragma unroll
        for (int k = 0; k < 8; ++k) {
          if (k < K) {
            cbx[k] = P.bx[(rb + k) * 64 + ln];
            car[k] = areaf(cbx[k]);
          }
        }
        u64 rw[8];
#pragma unroll
        for (int k = 0; k < 8; ++k) rw[k] = 0ull;
        int tb = 0;
        for (int kk = 0; kk < rb; ++kk) tb += ((8 - kk) | 1);
        int Sw = (8 - rb) | 1;
        int r0 = part * 32;
        int rlim = C1 - rb * 64; if (rlim > 64) rlim = 64;  // rows >= C1 unread
        for (int j = 0; j < 32; ++j) {
          int rl = r0 + j;
          if (rl >= rlim) break;                 // uniform (rlim block-uniform)
          float4 rbx = P.bx[rb * 64 + rl];       // same-address broadcast
          float rar = areaf(rbx);
#pragma unroll
          for (int k = 0; k < 8; ++k) {
            if (k < K) {
              u64 bal = __ballot(iou_gt(rbx, rar, cbx[k], car[k]));
              if (k == 0) bal &= ~((2ull << rl) - 1ull);   // keep only col > r
              rw[k] = (ln == rl) ? bal : rw[k];
            }
          }
        }
        if (ln >= r0 && ln < r0 + 32 && ln < rlim) {
          u64* myrow = &P.mat[tb * 64 + ln * Sw];
#pragma unroll
          for (int k = 0; k < 8; ++k)
            if (k < K) myrow[k] = rw[k];
        }
      }
    }
    __syncthreads();

    // ---- greedy: wave 0; off-diag row segments hoisted to registers ----
    if (w == 0) {
#pragma unroll
      for (int t = 0; t < WRD; ++t) {
        int b0 = t * 64;
        A[t] = (C1 >= b0 + 64) ? ~0ull : (C1 > b0 ? ((1ull << (C1 - b0)) - 1ull) : 0ull);
      }
      int tbase = 0;
#pragma unroll
      for (int wb = 0; wb < WRD; ++wb) {
        if (wb * 64 < C1) {
          const int Sw = (8 - wb) | 1;
          const u64* rowp = &P.mat[tbase];
          u64 aw = A[wb];
#pragma unroll
          for (int g = 0; g < 4; ++g) {
            u64 d[16];
#pragma unroll
            for (int k = 0; k < 16; ++k) d[k] = rowp[(g * 16 + k) * Sw];
#pragma unroll
            for (int k = 0; k < 16; ++k) {
              u64 msk = 0ull - ((aw >> (g * 16 + k)) & 1ull);
              aw &= ~(msk & d[k]);
            }
          }
          A[wb] = aw;
          bool alive = (aw >> ln) & 1ull;
          u64 seg[7];
#pragma unroll
          for (int t = 1; t < 8; ++t)
            if (wb + t < WRD && (wb + t) * 64 < C1)
              seg[t - 1] = rowp[ln * Sw + t];    // all loads in flight first
#pragma unroll
          for (int t = wb + 1; t < WRD; ++t) {
            if (t * 64 < C1) {
              u64 x = alive ? seg[t - wb - 1] : 0ull;
#pragma unroll
              for (int o = 1; o < 64; o <<= 1)
                x |= __shfl_xor((unsigned long long)x, o);
              A[t] &= ~x;
            }
          }
        }
        tbase += 64 * ((8 - wb) | 1);
      }
      if (ln == 0 && side == 1) {        // only side-1's keeps cross blocks
        u64* kG = keepRG + b * WRD;
#pragma unroll
        for (int t = 0; t < WRD; ++t)
          if (t * 64 < C1) kG[t] = A[t];
      }
    }
  }
  __syncthreads();   // all side-1 global writes happen-before tid0's release

  // ---- cross-block handshake: side-1 releases, side-0 acquires ----
  if (side == 1) {
    if (tid == 0) {
      __threadfence();
      __hip_atomic_store(&doneG[b], 1, __ATOMIC_RELEASE, __HIP_MEMORY_SCOPE_AGENT);
    }
    return;
  }
  if (tid == 0) {
    while (__hip_atomic_load(&doneG[b], __ATOMIC_ACQUIRE,
                             __HIP_MEMORY_SCOPE_AGENT) == 0)
      __builtin_amdgcn_s_sleep(2);
    __threadfence();
  }
  __syncthreads();

  // =============== finale (wave 0 of side-0 block) ===============
  float* ob = out + (size_t)b * NPROP * 9;
  int C1e = skipSel ? 0 : C1;
  if (w == 0) {
    int before = 0;
    unsigned kth = 0;
    for (int wb = 0; wb * 64 < C1e; ++wb) {
      u64 m = A[wb] & keepRG[b * WRD + wb];
      int pos = wb * 64 + ln;
      bool bit = (m >> ln) & 1ull;
      int rank = before + (int)__popcll(m & ((1ull << ln) - 1ull));
      unsigned vv = P.svs[pos];
      u64 selm = __ballot(bit && rank == DETS - 1);
      if (selm) kth = __shfl(vv, __ffsll(selm) - 1);
      bool qual = bit && (rank < DETS || vv == kth);
      if (qual) {
        int row = P.ssort[pos];
        float4 L = P.bx[pos];              // side-0's own (left) boxes, LDS
        float4 R4 = bxRG[b * MAXC + pos];  // side-1's boxes, global
        float* orow = ob + row * 9;
        orow[0]=L.x; orow[1]=L.y; orow[2]=L.z; orow[3]=L.w;
        orow[4]=R4.x; orow[5]=R4.y; orow[6]=R4.z; orow[7]=R4.w;
        orow[8]=score_from_v(vv);
      }
      before += (int)__popcll(m);
    }
    if (ln == 0) {
      S.needFB = (before < DETS && nvTot > C1e) ? 1 : 0;
      S.cnt = 0; S.prevCount = 0; S.done = 0; S.kthV = 0u;
    }
  }
  __syncthreads();
  if (!S.needFB) return;

  // ---- exact fallback (verbatim R6 path): full compact/sort/chunk NMS ----
  const float4* lp4 = (const float4*)lp;
  const float4* rp4 = (const float4*)rp;
  float4* ob4 = (float4*)ob;
  float4 z4 = make_float4(0.f, 0.f, 0.f, 0.f);
  for (int i = tid; i < NPROP * 9 / 4; i += 1024) ob4[i] = z4;
  for (int p = tid; p < NPROP; p += 1024) {
    unsigned v = v32G[b * NPROP + p];
    S.v32s[p] = v;
    bool cand = (v != 0xFFFFFFFFu);
    u64 mb = __ballot(cand);
    int lpos = (int)__popcll(mb & ((1ull << ln) - 1ull));
    int wb = 0;
    if (ln == 0 && mb) wb = atomicAdd(&S.cnt, (int)__popcll(mb));
    wb = __shfl(wb, 0);
    if (cand) S.keys[wb + lpos] = ((u64)v << 16) | (unsigned)p;
  }
  __syncthreads();
  int C2 = S.cnt;
  int CbEnd = (C2 + 63) & ~63;
  {
    int i0 = tid, i1 = tid + 1024;
    u64 k0 = (i0 < C2) ? S.keys[i0] : ~0ull;
    u64 k1 = (i1 < C2) ? S.keys[i1] : ~0ull;
    int r0 = 0, r1 = 0;
#pragma unroll 4
    for (int j = 0; j < C2; ++j) {
      u64 kj = S.keys[j];
      r0 += (kj < k0) ? 1 : 0;
      r1 += (kj < k1) ? 1 : 0;
    }
    if (i0 < C2) S.sidx[r0] = (unsigned short)(k0 & 0xFFFFull);
    if (i1 < C2) S.sidx[r1] = (unsigned short)(k1 & 0xFFFFull);
  }
  for (int i = C2 + tid; i < CbEnd; i += 1024) S.sidx[i] = 0;
  for (int wd = tid; wd < NPROP / 64; wd += 1024) {
    int b0 = wd << 6;
    u64 mf = 0ull;
    if (C2 >= b0 + 64) mf = ~0ull;
    else if (C2 > b0)  mf = (1ull << (C2 - b0)) - 1ull;
    S.keepbL[wd] = mf; S.keepbR[wd] = mf;
  }
  __syncthreads();
  {
    int lim = min(CbEnd, MAXC);
    for (int i = tid; i < lim; i += 1024) {
      if (i < C2) {
        int row = S.sidx[i];
        int grow = b * NPROP + row;
        int ci = ci16G[grow];
        float4 L = decode_side(reg, lp4, grow, ci, 0);
        float4 R = decode_side(reg, rp4, grow, ci, 1);
        S.bxL[i] = L; S.arL[i] = areaf(L);
        S.bxR[i] = R; S.arR[i] = areaf(R);
      } else {
        S.bxL[i] = z4; S.arL[i] = 1.0f;
        S.bxR[i] = z4; S.arR[i] = 1.0f;
      }
    }
  }
  __syncthreads();
  for (int base = 0; base < CbEnd; base += 64) {
    {
      int isR = (w >= 8);
      float4 cbx = get_sboxN(&S, reg, lp4, rp4, ci16G, b, base + ln, isR);
      float car = (base + ln < MAXC) ? (isR ? S.arR[base + ln] : S.arL[base + ln])
                                     : areaf(cbx);
      int w8 = w & 7;
#pragma unroll
      for (int k = 0; k < 8; ++k) {
        int row = w8 * 8 + k;
        float4 rbx;
        rbx.x = __shfl(cbx.x, row); rbx.y = __shfl(cbx.y, row);
        rbx.z = __shfl(cbx.z, row); rbx.w = __shfl(cbx.w, row);
        float rar = __shfl(car, row);
        bool bit = (ln > row) && iou_gt(rbx, rar, cbx, car);
        u64 bal = __ballot(bit);
        if (ln == 0) { if (isR) S.rowmR[row] = bal; else S.rowmL[row] = bal; }
      }
    }
    __syncthreads();
    if (tid < 128) {
      int isR = (tid >= 64);
      u64* km = isR ? S.keepbR : S.keepbL;
      u64* rm = isR ? S.rowmR  : S.rowmL;
      u64 a = km[base >> 6];
#pragma unroll
      for (int j = 0; j < 64; ++j)
        a &= ~((0ull - ((a >> j) & 1ull)) & rm[j]);
      if (ln == 0) {
        km[base >> 6] = a;
        if (isR) { S.aR = a; S.ccR = __popcll(a); }
        else     { S.aL = a; S.ccL = __popcll(a); }
      }
      if ((a >> ln) & 1ull) {
        int pos = __popcll(a & ((1ull << ln) - 1ull));
        float4 v = get_sboxN(&S, reg, lp4, rp4, ci16G, b, base + ln, isR);
        if (isR) { S.cbR[pos] = v; S.cbRa[pos] = areaf(v); }
        else     { S.cbL[pos] = v; S.cbLa[pos] = areaf(v); }
      }
    }
    __syncthreads();
    if (w == 0) {
      u64 m = S.aL & S.aR;
      int before = S.prevCount;
      bool bit = (m >> ln) & 1ull;
      int rank = before + (int)__popcll(m & ((1ull << ln) - 1ull));
      int row = S.sidx[base + ln];
      unsigned vv = S.v32s[row];
      u64 selm = __ballot(bit && rank == DETS - 1);
      unsigned keffV = S.kthV;
      if (selm) keffV = __shfl(vv, __ffsll(selm) - 1);
      bool qual = bit && (rank < DETS || vv == keffV);
      if (qual) {
        float4 L = get_sboxN(&S, reg, lp4, rp4, ci16G, b, base + ln, 0);
        float4 R = get_sboxN(&S, reg, lp4, rp4, ci16G, b, base + ln, 1);
        float s = score_from_v(vv);
        float* orow = ob + row * 9;
        orow[0]=L.x; orow[1]=L.y; orow[2]=L.z; orow[3]=L.w;
        orow[4]=R.x; orow[5]=R.y; orow[6]=R.z; orow[7]=R.w;
        orow[8]=s;
      }
      if (ln == 0) {
        if (selm) S.kthV = keffV;
        int nc = before + (int)__popcll(m);
        S.prevCount = nc;
        if (nc >= DETS) {
          int nxt = base + 64;
          bool cont = false;
          if (nxt < C2) cont = (S.v32s[S.sidx[nxt]] == keffV);
          if (!cont) S.done = 1;
        }
      }
    } else {
      int cL = S.ccL, cR = S.ccR;
      if ((cL | cR) != 0) {
        for (int p = base + 64 + (tid - 64); p < CbEnd; p += 960) {
          float4 mbL = get_sboxN(&S, reg, lp4, rp4, ci16G, b, p, 0);
          float al = (p < MAXC) ? S.arL[p] : areaf(mbL);
          bool supL = false;
          for (int q = 0; q < cL; ++q)
            supL = supL || iou_gt(mbL, al, S.cbL[q], S.cbLa[q]);
          if (supL) atomicAnd(&S.keepbL[p >> 6], ~(1ull << (p & 63)));
          float4 mbR = get_sboxN(&S, reg, lp4, rp4, ci16G, b, p, 1);
          float ar_ = (p < MAXC) ? S.arR[p] : areaf(mbR);
          bool supR = false;
          for (int q = 0; q < cR; ++q)
            supR = supR || iou_gt(mbR, ar_, S.cbR[q], S.cbRa[q]);
          if (supR) atomicAnd(&S.keepbR[p >> 6], ~(1ull << (p & 63)));
        }
      }
    }
    __syncthreads();
    if (S.done) break;
  }
}

// ---------------------------------------------------------------------------
extern "C" void kernel_launch(void* const* d_in, const int* in_sizes, int n_in,
                              void* d_out, int out_size, void* d_ws, size_t ws_size,
                              hipStream_t stream) {
  const float* logits = (const float*)d_in[0];   // [8192, 81]
  const float* reg    = (const float*)d_in[1];   // [8192, 648]
  const float* lprop  = (const float*)d_in[2];   // [8192, 4]
  const float* rprop  = (const float*)d_in[3];   // [8192, 4]
  float* out = (float*)d_out;                    // [4, 2048, 9]

  char* ws = (char*)d_ws;
  unsigned*       v32G   = (unsigned*)(ws + 0);          // 32 KB
  unsigned short* ci16G  = (unsigned short*)(ws + 32768);// 16 KB
  float4*         bxRG   = (float4*)(ws + 49152);        // 32 KB
  u64*            keepRG = (u64*)(ws + 81920);           // 256 B
  int*            doneG  = (int*)(ws + 82176);           // 16 B

  score_kernel<<<NIMG * NPROP / 4, 256, 0, stream>>>(logits, v32G, ci16G,
                                                     doneG, out);
  nms_fused_kernel<<<2 * NIMG, 1024, 0, stream>>>(v32G, ci16G, reg, lprop, rprop,
                                                  bxRG, keepRG, doneG, out);
}

// Round 8
// 118.855 us; speedup vs baseline: 1.0139x; 1.0139x over previous
//
#include <hip/hip_runtime.h>
#include <math.h>

// Problem constants (B=4, N=2048, C=81)
#define NPROP 2048
#define NIMG 4
#define NCLS 81
#define REGW 648          // C*8
#define SCORE_THRESH 0.05f
#define NMS_T 0.5f
#define DETS 100
#define XC 1023.0f        // IMG_W - 1
#define YC 799.0f         // IMG_H - 1
#define BBOX_CLIP 4.135166556742356f  // log(1000/16)
#define NBIN 8192         // 13-bit score-bin histogram (v >> 19)
#define SEL 320           // tranche target (coarse bin crossing; C1 lands ~500)
#define MAXC 512          // fast-path candidate cap
#define WRD 8             // MAXC/64 keep words
#define TRIP 2560         // padded triangular words: 64*(9+7+7+5+5+3+3+1)

typedef unsigned long long u64;

__device__ __forceinline__ float areaf(float4 v) {
  return fmaxf(v.z - v.x + 1.0f, 0.0f) * fmaxf(v.w - v.y + 1.0f, 0.0f);
}
__device__ __forceinline__ bool iou_gt(float4 a, float aa, float4 b, float ba) {
  float ix1 = fmaxf(a.x, b.x), iy1 = fmaxf(a.y, b.y);
  float ix2 = fminf(a.z, b.z), iy2 = fminf(a.w, b.w);
  float iw = fmaxf(ix2 - ix1 + 1.0f, 0.0f);
  float ih = fmaxf(iy2 - iy1 + 1.0f, 0.0f);
  float inter = iw * ih;
  return inter > NMS_T * fmaxf(aa + ba - inter, 1e-6f);
}
__device__ __forceinline__ float score_from_v(unsigned v) {
  unsigned uu = ~v;
  unsigned bits = (uu & 0x80000000u) ? (uu & 0x7fffffffu) : ~uu;
  return __uint_as_float(bits);
}
__device__ __forceinline__ float4 decode_math(float4 rr, float4 P) {
  float w  = P.z - P.x + 1.0f;
  float h  = P.w - P.y + 1.0f;
  float cx = P.x + 0.5f * w;
  float cy = P.y + 0.5f * h;
  float dx = rr.x / 10.0f;
  float dy = rr.y / 10.0f;
  float dw = fminf(rr.z / 5.0f, BBOX_CLIP);
  float dh = fminf(rr.w / 5.0f, BBOX_CLIP);
  float pcx = dx * w + cx;
  float pcy = dy * h + cy;
  float pw = expf(dw) * w;
  float ph = expf(dh) * h;
  float4 o;
  o.x = fminf(fmaxf(pcx - 0.5f * pw, 0.0f), XC);
  o.y = fminf(fmaxf(pcy - 0.5f * ph, 0.0f), YC);
  o.z = fminf(fmaxf(pcx + 0.5f * pw - 1.0f, 0.0f), XC);
  o.w = fminf(fmaxf(pcy + 0.5f * ph - 1.0f, 0.0f), YC);
  return o;
}
__device__ __forceinline__ float4 decode_side(const float* __restrict__ reg,
                                              const float4* __restrict__ props,
                                              int grow, int ci, int isR) {
  const float4 rr = *(const float4*)(reg + (size_t)grow * REGW + ci * 8 + isR * 4);
  return decode_math(rr, props[grow]);
}

// ---------------------------------------------------------------------------
// K1: wide per-row softmax-argmax -> v32 + ci16; first 72 blocks also zero out.
// ---------------------------------------------------------------------------
__global__ __launch_bounds__(256) void score_kernel(
    const float* __restrict__ logits,
    unsigned* __restrict__ v32G, unsigned short* __restrict__ ci16G,
    float* __restrict__ out) {
  int row  = blockIdx.x * 4 + (threadIdx.x >> 6);
  int lane = threadIdx.x & 63;
  if (blockIdx.x < 72) {                // zero output: 72*256 = 18432 float4s
    int g = blockIdx.x * 256 + threadIdx.x;
    ((float4*)out)[g] = make_float4(0.f, 0.f, 0.f, 0.f);
  }
  const float* lr = logits + (size_t)row * NCLS;
  float a = lr[lane];
  float b = (lane < NCLS - 64) ? lr[lane + 64] : -INFINITY;
  float v; int ci;
  if (b > a) { v = b; ci = lane + 64; } else { v = a; ci = lane; }
  for (int o = 32; o; o >>= 1) {        // wave argmax, min-index ties
    float ov = __shfl_xor(v, o);
    int   oc = __shfl_xor(ci, o);
    if (ov > v || (ov == v && oc < ci)) { v = ov; ci = oc; }
  }
  float e = expf(a - v) + ((lane < NCLS - 64) ? expf(b - v) : 0.0f);
  for (int o = 32; o; o >>= 1) e += __shfl_xor(e, o);
  if (lane == 0) {
    float score = 1.0f / e;             // softmax at argmax (numerator exp(0))
    unsigned vv = 0xFFFFFFFFu;
    if (ci >= 1 && score > SCORE_THRESH) {
      unsigned uu = __float_as_uint(score);
      uu = (uu & 0x80000000u) ? ~uu : (uu | 0x80000000u);
      vv = ~uu;                         // ascending vv == descending score
    }
    v32G[row]  = vv;
    ci16G[row] = (unsigned short)ci;
  }
}

// ---------------------------------------------------------------------------
// K2a (4 blocks = per image, 1024 thr): select + rank-sort + decode both sides.
// Writes srowG/svG (sorted order), bxLG/bxRG (sorted decoded boxes), C1G/C2G.
// Select/sort bodies verbatim from the R6-verified kernel (no reg batching —
// that spilled in R7).
// ---------------------------------------------------------------------------
struct PSel {
  int hist[NBIN];              // 32 KB
  u64 keys[MAXC];              // 4 KB   key = v<<32 | p<<21 | ci<<14
  int rnk[MAXC];               // 2 KB
  int wsum[16];
  int Ts, cnts, ovf;
};

__global__ __launch_bounds__(1024) void selsort_kernel(
    const unsigned* __restrict__ v32G, const unsigned short* __restrict__ ci16G,
    const float* __restrict__ reg, const float* __restrict__ lp,
    const float* __restrict__ rp,
    unsigned short* __restrict__ srowG, unsigned* __restrict__ svG,
    float4* __restrict__ bxLG, float4* __restrict__ bxRG,
    int* __restrict__ C1G, int* __restrict__ C2G) {
  __shared__ PSel P;
  int b = blockIdx.x;
  int tid = threadIdx.x, ln = tid & 63, w = tid >> 6;
  const unsigned* v32 = v32G + b * NPROP;
  const unsigned short* ci16 = ci16G + b * NPROP;

  unsigned vA0 = v32[tid], vA1 = v32[tid + 1024];
  unsigned cA0 = ci16[tid], cA1 = ci16[tid + 1024];
  if (tid == 0) { P.Ts = NBIN - 1; P.cnts = 0; P.ovf = 0; }
  for (int i = tid; i < NBIN / 4; i += 1024)
    ((int4*)P.hist)[i] = make_int4(0, 0, 0, 0);
  __syncthreads();
  if (vA0 != 0xFFFFFFFFu) atomicAdd(&P.hist[vA0 >> 19], 1);
  if (vA1 != 0xFFFFFFFFu) atomicAdd(&P.hist[vA1 >> 19], 1);
  __syncthreads();
  {  // scan 8192 bins (8/thread) -> threshold bin Ts (cum >= SEL), total
    int base = tid * 8;
    int c[8]; int acc = 0;
#pragma unroll
    for (int k = 0; k < 8; ++k) { acc += P.hist[base + k]; c[k] = acc; }
    int tot = acc, v = tot;
#pragma unroll
    for (int o = 1; o < 64; o <<= 1) { int n = __shfl_up(v, o); if (ln >= o) v += n; }
    if (ln == 63) P.wsum[w] = v;
    __syncthreads();
    if (tid < 16) {
      int x = P.wsum[tid];
#pragma unroll
      for (int o = 1; o < 16; o <<= 1) { int n = __shfl_up(x, o); if (tid >= o) x += n; }
      P.wsum[tid] = x;
    }
    __syncthreads();
    int incl = ((w > 0) ? P.wsum[w - 1] : 0) + v;
    int off = incl - tot;
    int prev = off;
#pragma unroll
    for (int k = 0; k < 8; ++k) {
      int cur = off + c[k];
      if (cur >= SEL && prev < SEL) P.Ts = base + k;
      prev = cur;
    }
  }
  __syncthreads();
  int T = P.Ts, nvTot = P.wsum[15];
  {  // compact bin <= T
    unsigned vv[2] = {vA0, vA1};
    unsigned cc[2] = {cA0, cA1};
#pragma unroll
    for (int it = 0; it < 2; ++it) {
      int p = tid + it * 1024;
      unsigned v = vv[it];
      bool cand = (v != 0xFFFFFFFFu) && ((int)(v >> 19) <= T);
      u64 mb = __ballot(cand);
      int lpos = (int)__popcll(mb & ((1ull << ln) - 1ull));
      int wb = 0;
      if (ln == 0 && mb) wb = atomicAdd(&P.cnts, (int)__popcll(mb));
      wb = __shfl(wb, 0);
      if (cand) {
        int dst = wb + lpos;
        if (dst < MAXC)
          P.keys[dst] = ((u64)v << 32) | ((u64)p << 21) | ((u64)cc[it] << 14);
        else P.ovf = 1;
      }
    }
  }
  __syncthreads();
  int C1 = P.cnts;
  if (C1 > MAXC || P.ovf) {     // overflow -> K3 runs exact fallback
    if (tid == 0) { C1G[b] = 0; C2G[b] = nvTot; }
    return;
  }
  if (tid == 0) { C1G[b] = C1; C2G[b] = nvTot; }
  // ---- rank-sort: 4 waves, 2 keys/thread (R6-verified, no spill) ----
  if (tid < 256) {
    int i0 = tid, i1 = tid + 256;
    u64 k0 = (i0 < C1) ? P.keys[i0] : ~0ull;
    u64 k1 = (i1 < C1) ? P.keys[i1] : ~0ull;
    int r0 = 0, r1 = 0;
#pragma unroll 4
    for (int j = 0; j < C1; ++j) {
      u64 kj = P.keys[j];
      r0 += (kj < k0) ? 1 : 0;
      r1 += (kj < k1) ? 1 : 0;
    }
    if (i0 < C1) P.rnk[i0] = r0;
    if (i1 < C1) P.rnk[i1] = r1;
  }
  __syncthreads();
  // ---- decode both sides: tid<512 -> left, tid>=512 -> right ----
  {
    int s = tid & 511, sd = tid >> 9;
    if (s < C1) {
      u64 k = P.keys[s];
      unsigned myv = (unsigned)(k >> 32);
      int myp = (int)((k >> 21) & 0x7FF);
      int myci = (int)((k >> 14) & 0x7F);
      int R = P.rnk[s];
      int grow = b * NPROP + myp;
      float4 B = decode_side(reg, (const float4*)(sd ? rp : lp), grow, myci, sd);
      (sd ? bxRG : bxLG)[b * MAXC + R] = B;
      if (sd == 0) {
        srowG[b * MAXC + R] = (unsigned short)myp;
        svG[b * MAXC + R] = myv;
      }
    }
  }
}

// ---------------------------------------------------------------------------
// K2b (64 blocks = img x side x rb, 256 thr): ballot-matrix row-block build.
// bx staged global->LDS; mat words written to global matG (triangular layout).
// Ballot scheme verbatim R6; 4 waves x 16 rows replaces 2 waves x 32 rows.
// ---------------------------------------------------------------------------
__global__ __launch_bounds__(256) void matrix_kernel(
    const float4* __restrict__ bxLG, const float4* __restrict__ bxRG,
    const int* __restrict__ C1G, u64* __restrict__ matG) {
  __shared__ float4 bx[MAXC];
  int id = blockIdx.x;
  int b = id >> 4, side = (id >> 3) & 1, rb = id & 7;
  int tid = threadIdx.x, ln = tid & 63, wv = tid >> 6;
  int C1 = C1G[b];
  int WRDu = (C1 + 63) >> 6;
  if (rb >= WRDu) return;               // uniform; covers C1 == 0
  const float4* src = (side ? bxRG : bxLG) + b * MAXC;
  for (int i = tid; i < MAXC; i += 256) bx[i] = src[i];  // >=C1 garbage: masked
  __syncthreads();
  int K = WRDu - rb;
  float4 cbx[8]; float car[8];
#pragma unroll
  for (int k = 0; k < 8; ++k) {
    if (k < K) { cbx[k] = bx[(rb + k) * 64 + ln]; car[k] = areaf(cbx[k]); }
  }
  u64 rw[8];
#pragma unroll
  for (int k = 0; k < 8; ++k) rw[k] = 0ull;
  int tb = 0;
  for (int kk = 0; kk < rb; ++kk) tb += ((8 - kk) | 1);
  int Sw = (8 - rb) | 1;
  int r0 = wv * 16;
  int rlim = C1 - rb * 64; if (rlim > 64) rlim = 64;
  for (int j = 0; j < 16; ++j) {
    int rl = r0 + j;
    if (rl >= rlim) break;              // wave-uniform
    float4 rbx = bx[rb * 64 + rl];      // same-address broadcast
    float rar = areaf(rbx);
#pragma unroll
    for (int k = 0; k < 8; ++k) {
      if (k < K) {
        u64 bal = __ballot(iou_gt(rbx, rar, cbx[k], car[k]));
        if (k == 0) bal &= ~((2ull << rl) - 1ull);   // keep only col > r
        rw[k] = (ln == rl) ? bal : rw[k];
      }
    }
  }
  if (ln >= r0 && ln < r0 + 16 && ln < rlim) {
    u64* myrow = matG + (size_t)(b * 2 + side) * TRIP + tb * 64 + ln * Sw;
#pragma unroll
    for (int k = 0; k < 8; ++k)
      if (k < K) myrow[k] = rw[k];
  }
}

// ---------------------------------------------------------------------------
// K3 (4 blocks = per image, 1024 thr): stage mat L+R -> LDS, greedy-L (wave 0)
// CONCURRENT with greedy-R (wave 1), finale (wave 0), dormant exact fallback.
// Greedy / finale / fallback bodies verbatim from verified kernels.
// ---------------------------------------------------------------------------
struct SN {
  u64 keys[NPROP];
  unsigned short sidx[NPROP];
  unsigned v32s[NPROP];
  float4 bxL[MAXC], bxR[MAXC];
  float  arL[MAXC], arR[MAXC];
  u64 keepbL[NPROP / 64], keepbR[NPROP / 64];
  u64 rowmL[64], rowmR[64];
  float4 cbL[64], cbR[64];
  float  cbLa[64], cbRa[64];
  u64 aL, aR;
  int cnt, prevCount, done, ccL, ccR, needFB;
  unsigned kthV;
};

__device__ __forceinline__ float4 get_sboxN(SN* S, const float* reg,
                                            const float4* lp4, const float4* rp4,
                                            const unsigned short* ci16G,
                                            int b, int pos, int isR) {
  if (pos < MAXC) return isR ? S->bxR[pos] : S->bxL[pos];
  int row = S->sidx[pos];
  int grow = b * NPROP + row;
  return decode_side(reg, isR ? rp4 : lp4, grow, ci16G[grow], isR);
}

__global__ __launch_bounds__(1024) void finale_kernel(
    const float* __restrict__ reg, const float* __restrict__ lp,
    const float* __restrict__ rp, const unsigned* __restrict__ v32G,
    const unsigned short* __restrict__ ci16G,
    const unsigned short* __restrict__ srowG, const unsigned* __restrict__ svG,
    const float4* __restrict__ bxLG, const float4* __restrict__ bxRG,
    const int* __restrict__ C1G, const int* __restrict__ C2G,
    const u64* __restrict__ matG, float* __restrict__ out) {
  __shared__ u64 matL[TRIP], matR[TRIP];   // 40 KB
  __shared__ u64 ALs[WRD], ARs[WRD];
  __shared__ SN S;                          // ~53 KB (separate; total < 96 KB)
  int b = blockIdx.x, tid = threadIdx.x, ln = tid & 63, w = tid >> 6;
  float* ob = out + (size_t)b * NPROP * 9;
  int C1 = C1G[b];
  int nvTot = C2G[b];

  if (C1 > 0) {
    const u64* mL = matG + (size_t)(b * 2 + 0) * TRIP;
    const u64* mR = matG + (size_t)(b * 2 + 1) * TRIP;
    for (int i = tid; i < TRIP; i += 1024) { matL[i] = mL[i]; matR[i] = mR[i]; }
    __syncthreads();
    if (w < 2) {   // wave 0: left matrix, wave 1: right matrix — concurrent
      const u64* matS = w ? matR : matL;
      u64 A[WRD];
#pragma unroll
      for (int t = 0; t < WRD; ++t) {
        int b0 = t * 64;
        A[t] = (C1 >= b0 + 64) ? ~0ull : (C1 > b0 ? ((1ull << (C1 - b0)) - 1ull) : 0ull);
      }
      int tbase = 0;
#pragma unroll
      for (int wb = 0; wb < WRD; ++wb) {
        if (wb * 64 < C1) {
          const int Sw = (8 - wb) | 1;
          const u64* rowp = &matS[tbase];
          u64 aw = A[wb];
#pragma unroll
          for (int g = 0; g < 4; ++g) {
            u64 d[16];
#pragma unroll
            for (int k = 0; k < 16; ++k) d[k] = rowp[(g * 16 + k) * Sw];
#pragma unroll
            for (int k = 0; k < 16; ++k) {
              u64 msk = 0ull - ((aw >> (g * 16 + k)) & 1ull);
              aw &= ~(msk & d[k]);
            }
          }
          A[wb] = aw;
          bool alive = (aw >> ln) & 1ull;
#pragma unroll
          for (int t = wb + 1; t < WRD; ++t) {
            if (t * 64 < C1) {
              u64 x = alive ? rowp[ln * Sw + (t - wb)] : 0ull;
#pragma unroll
              for (int o = 1; o < 64; o <<= 1)
                x |= __shfl_xor((unsigned long long)x, o);
              A[t] &= ~x;
            }
          }
        }
        tbase += 64 * ((8 - wb) | 1);
      }
      if (ln == 0) {
        u64* dst = w ? ARs : ALs;
#pragma unroll
        for (int t = 0; t < WRD; ++t) dst[t] = A[t];
      }
    }
    __syncthreads();
  }

  // ---- finale (wave 0): AND keeps, rank, kth ties, write output rows ----
  if (w == 0) {
    int before = 0;
    unsigned kth = 0;
    for (int wb = 0; wb * 64 < C1; ++wb) {
      u64 m = ALs[wb] & ARs[wb];
      int pos = wb * 64 + ln;
      bool bit = (m >> ln) & 1ull;
      int rank = before + (int)__popcll(m & ((1ull << ln) - 1ull));
      unsigned vv = svG[b * MAXC + pos];
      u64 selm = __ballot(bit && rank == DETS - 1);
      if (selm) kth = __shfl(vv, __ffsll(selm) - 1);
      bool qual = bit && (rank < DETS || vv == kth);
      if (qual) {
        int row = srowG[b * MAXC + pos];
        float4 L = bxLG[b * MAXC + pos], R4 = bxRG[b * MAXC + pos];
        float* orow = ob + row * 9;
        orow[0]=L.x; orow[1]=L.y; orow[2]=L.z; orow[3]=L.w;
        orow[4]=R4.x; orow[5]=R4.y; orow[6]=R4.z; orow[7]=R4.w;
        orow[8]=score_from_v(vv);
      }
      before += (int)__popcll(m);
    }
    if (ln == 0) {
      S.needFB = (before < DETS && nvTot > C1) ? 1 : 0;
      S.cnt = 0; S.prevCount = 0; S.done = 0; S.kthV = 0u;
    }
  }
  __syncthreads();
  if (!S.needFB) return;

  // ---- exact fallback (verbatim verified path) ----
  const float4* lp4 = (const float4*)lp;
  const float4* rp4 = (const float4*)rp;
  float4* ob4 = (float4*)ob;
  float4 z4 = make_float4(0.f, 0.f, 0.f, 0.f);
  for (int i = tid; i < NPROP * 9 / 4; i += 1024) ob4[i] = z4;
  for (int p = tid; p < NPROP; p += 1024) {
    unsigned v = v32G[b * NPROP + p];
    S.v32s[p] = v;
    bool cand = (v != 0xFFFFFFFFu);
    u64 mb = __ballot(cand);
    int lpos = (int)__popcll(mb & ((1ull << ln) - 1ull));
    int wb = 0;
    if (ln == 0 && mb) wb = atomicAdd(&S.cnt, (int)__popcll(mb));
    wb = __shfl(wb, 0);
    if (cand) S.keys[wb + lpos] = ((u64)v << 16) | (unsigned)p;
  }
  __syncthreads();
  int C2 = S.cnt;
  int CbEnd = (C2 + 63) & ~63;
  {
    int i0 = tid, i1 = tid + 1024;
    u64 k0 = (i0 < C2) ? S.keys[i0] : ~0ull;
    u64 k1 = (i1 < C2) ? S.keys[i1] : ~0ull;
    int r0 = 0, r1 = 0;
#pragma unroll 4
    for (int j = 0; j < C2; ++j) {
      u64 kj = S.keys[j];
      r0 += (kj < k0) ? 1 : 0;
      r1 += (kj < k1) ? 1 : 0;
    }
    if (i0 < C2) S.sidx[r0] = (unsigned short)(k0 & 0xFFFFull);
    if (i1 < C2) S.sidx[r1] = (unsigned short)(k1 & 0xFFFFull);
  }
  for (int i = C2 + tid; i < CbEnd; i += 1024) S.sidx[i] = 0;
  for (int wd = tid; wd < NPROP / 64; wd += 1024) {
    int b0 = wd << 6;
    u64 mf = 0ull;
    if (C2 >= b0 + 64) mf = ~0ull;
    else if (C2 > b0)  mf = (1ull << (C2 - b0)) - 1ull;
    S.keepbL[wd] = mf; S.keepbR[wd] = mf;
  }
  __syncthreads();
  {
    int lim = min(CbEnd, MAXC);
    for (int i = tid; i < lim; i += 1024) {
      if (i < C2) {
        int row = S.sidx[i];
        int grow = b * NPROP + row;
        int ci = ci16G[grow];
        float4 L = decode_side(reg, lp4, grow, ci, 0);
        float4 R = decode_side(reg, rp4, grow, ci, 1);
        S.bxL[i] = L; S.arL[i] = areaf(L);
        S.bxR[i] = R; S.arR[i] = areaf(R);
      } else {
        S.bxL[i] = z4; S.arL[i] = 1.0f;
        S.bxR[i] = z4; S.arR[i] = 1.0f;
      }
    }
  }
  __syncthreads();
  for (int base = 0; base < CbEnd; base += 64) {
    {
      int isR = (w >= 8);
      float4 cbx = get_sboxN(&S, reg, lp4, rp4, ci16G, b, base + ln, isR);
      float car = (base + ln < MAXC) ? (isR ? S.arR[base + ln] : S.arL[base + ln])
                                     : areaf(cbx);
      int w8 = w & 7;
#pragma unroll
      for (int k = 0; k < 8; ++k) {
        int row = w8 * 8 + k;
        float4 rbx;
        rbx.x = __shfl(cbx.x, row); rbx.y = __shfl(cbx.y, row);
        rbx.z = __shfl(cbx.z, row); rbx.w = __shfl(cbx.w, row);
        float rar = __shfl(car, row);
        bool bit = (ln > row) && iou_gt(rbx, rar, cbx, car);
        u64 bal = __ballot(bit);
        if (ln == 0) { if (isR) S.rowmR[row] = bal; else S.rowmL[row] = bal; }
      }
    }
    __syncthreads();
    if (tid < 128) {
      int isR = (tid >= 64);
      u64* km = isR ? S.keepbR : S.keepbL;
      u64* rm = isR ? S.rowmR  : S.rowmL;
      u64 a = km[base >> 6];
#pragma unroll
      for (int j = 0; j < 64; ++j)
        a &= ~((0ull - ((a >> j) & 1ull)) & rm[j]);
      if (ln == 0) {
        km[base >> 6] = a;
        if (isR) { S.aR = a; S.ccR = __popcll(a); }
        else     { S.aL = a; S.ccL = __popcll(a); }
      }
      if ((a >> ln) & 1ull) {
        int pos = __popcll(a & ((1ull << ln) - 1ull));
        float4 v = get_sboxN(&S, reg, lp4, rp4, ci16G, b, base + ln, isR);
        if (isR) { S.cbR[pos] = v; S.cbRa[pos] = areaf(v); }
        else     { S.cbL[pos] = v; S.cbLa[pos] = areaf(v); }
      }
    }
    __syncthreads();
    if (w == 0) {
      u64 m = S.aL & S.aR;
      int before = S.prevCount;
      bool bit = (m >> ln) & 1ull;
      int rank = before + (int)__popcll(m & ((1ull << ln) - 1ull));
      int row = S.sidx[base + ln];
      unsigned vv = S.v32s[row];
      u64 selm = __ballot(bit && rank == DETS - 1);
      unsigned keffV = S.kthV;
      if (selm) keffV = __shfl(vv, __ffsll(selm) - 1);
      bool qual = bit && (rank < DETS || vv == keffV);
      if (qual) {
        float4 L = get_sboxN(&S, reg, lp4, rp4, ci16G, b, base + ln, 0);
        float4 R = get_sboxN(&S, reg, lp4, rp4, ci16G, b, base + ln, 1);
        float s = score_from_v(vv);
        float* orow = ob + row * 9;
        orow[0]=L.x; orow[1]=L.y; orow[2]=L.z; orow[3]=L.w;
        orow[4]=R.x; orow[5]=R.y; orow[6]=R.z; orow[7]=R.w;
        orow[8]=s;
      }
      if (ln == 0) {
        if (selm) S.kthV = keffV;
        int nc = before + (int)__popcll(m);
        S.prevCount = nc;
        if (nc >= DETS) {
          int nxt = base + 64;
          bool cont = false;
          if (nxt < C2) cont = (S.v32s[S.sidx[nxt]] == keffV);
          if (!cont) S.done = 1;
        }
      }
    } else {
      int cL = S.ccL, cR = S.ccR;
      if ((cL | cR) != 0) {
        for (int p = base + 64 + (tid - 64); p < CbEnd; p += 960) {
          float4 mbL = get_sboxN(&S, reg, lp4, rp4, ci16G, b, p, 0);
          float al = (p < MAXC) ? S.arL[p] : areaf(mbL);
          bool supL = false;
          for (int q = 0; q < cL; ++q)
            supL = supL || iou_gt(mbL, al, S.cbL[q], S.cbLa[q]);
          if (supL) atomicAnd(&S.keepbL[p >> 6], ~(1ull << (p & 63)));
          float4 mbR = get_sboxN(&S, reg, lp4, rp4, ci16G, b, p, 1);
          float ar_ = (p < MAXC) ? S.arR[p] : areaf(mbR);
          bool supR = false;
          for (int q = 0; q < cR; ++q)
            supR = supR || iou_gt(mbR, ar_, S.cbR[q], S.cbRa[q]);
          if (supR) atomicAnd(&S.keepbR[p >> 6], ~(1ull << (p & 63)));
        }
      }
    }
    __syncthreads();
    if (S.done) break;
  }
}

// ---------------------------------------------------------------------------
extern "C" void kernel_launch(void* const* d_in, const int* in_sizes, int n_in,
                              void* d_out, int out_size, void* d_ws, size_t ws_size,
                              hipStream_t stream) {
  const float* logits = (const float*)d_in[0];   // [8192, 81]
  const float* reg    = (const float*)d_in[1];   // [8192, 648]
  const float* lprop  = (const float*)d_in[2];   // [8192, 4]
  const float* rprop  = (const float*)d_in[3];   // [8192, 4]
  float* out = (float*)d_out;                    // [4, 2048, 9]

  char* ws = (char*)d_ws;                        // ~288 KB used
  unsigned*       v32G   = (unsigned*)(ws + 0);          // 32 KB
  unsigned short* ci16G  = (unsigned short*)(ws + 32768);// 16 KB
  unsigned short* srowG  = (unsigned short*)(ws + 49152);// 4 KB
  unsigned*       svG    = (unsigned*)(ws + 53248);      // 8 KB
  float4*         bxLG   = (float4*)(ws + 61440);        // 32 KB
  float4*         bxRG   = (float4*)(ws + 94208);        // 32 KB
  int*            C1G    = (int*)(ws + 126976);          // 16 B
  int*            C2G    = (int*)(ws + 127040);          // 16 B
  u64*            matG   = (u64*)(ws + 131072);          // 160 KB (8 x TRIP)

  score_kernel  <<<NIMG * NPROP / 4, 256,  0, stream>>>(logits, v32G, ci16G, out);
  selsort_kernel<<<NIMG,             1024, 0, stream>>>(v32G, ci16G, reg, lprop,
                                                        rprop, srowG, svG,
                                                        bxLG, bxRG, C1G, C2G);
  matrix_kernel <<<NIMG * 16,        256,  0, stream>>>(bxLG, bxRG, C1G, matG);
  finale_kernel <<<NIMG,             1024, 0, stream>>>(reg, lprop, rprop, v32G,
                                                        ci16G, srowG, svG,
                                                        bxLG, bxRG, C1G, C2G,
                                                        matG, out);
}

// Round 9
// 116.218 us; speedup vs baseline: 1.0369x; 1.0227x over previous
//
#include <hip/hip_runtime.h>
#include <math.h>

// Problem constants (B=4, N=2048, C=81)
#define NPROP 2048
#define NIMG 4
#define NCLS 81
#define REGW 648          // C*8
#define SCORE_THRESH 0.05f
#define NMS_T 0.5f
#define DETS 100
#define XC 1023.0f        // IMG_W - 1
#define YC 799.0f         // IMG_H - 1
#define BBOX_CLIP 4.135166556742356f  // log(1000/16)
#define NBIN 8192         // 13-bit score-bin histogram (v >> 19)
#define SEL 320           // tranche target (coarse bin crossing; C1 lands ~500)
#define MAXC 512          // fast-path candidate cap
#define WRD 8             // MAXC/64 keep words
#define TRIP 2560         // padded triangular words: 64*(9+7+7+5+5+3+3+1)

typedef unsigned long long u64;

__device__ __forceinline__ float areaf(float4 v) {
  return fmaxf(v.z - v.x + 1.0f, 0.0f) * fmaxf(v.w - v.y + 1.0f, 0.0f);
}
__device__ __forceinline__ bool iou_gt(float4 a, float aa, float4 b, float ba) {
  float ix1 = fmaxf(a.x, b.x), iy1 = fmaxf(a.y, b.y);
  float ix2 = fminf(a.z, b.z), iy2 = fminf(a.w, b.w);
  float iw = fmaxf(ix2 - ix1 + 1.0f, 0.0f);
  float ih = fmaxf(iy2 - iy1 + 1.0f, 0.0f);
  float inter = iw * ih;
  return inter > NMS_T * fmaxf(aa + ba - inter, 1e-6f);
}
__device__ __forceinline__ float score_from_v(unsigned v) {
  unsigned uu = ~v;
  unsigned bits = (uu & 0x80000000u) ? (uu & 0x7fffffffu) : ~uu;
  return __uint_as_float(bits);
}
// decode arithmetic from already-loaded regression float4 + proposal float4
__device__ __forceinline__ float4 decode_math(float4 rr, float4 P) {
  float w  = P.z - P.x + 1.0f;
  float h  = P.w - P.y + 1.0f;
  float cx = P.x + 0.5f * w;
  float cy = P.y + 0.5f * h;
  float dx = rr.x / 10.0f;
  float dy = rr.y / 10.0f;
  float dw = fminf(rr.z / 5.0f, BBOX_CLIP);
  float dh = fminf(rr.w / 5.0f, BBOX_CLIP);
  float pcx = dx * w + cx;
  float pcy = dy * h + cy;
  float pw = expf(dw) * w;
  float ph = expf(dh) * h;
  float4 o;
  o.x = fminf(fmaxf(pcx - 0.5f * pw, 0.0f), XC);
  o.y = fminf(fmaxf(pcy - 0.5f * ph, 0.0f), YC);
  o.z = fminf(fmaxf(pcx + 0.5f * pw - 1.0f, 0.0f), XC);
  o.w = fminf(fmaxf(pcy + 0.5f * ph - 1.0f, 0.0f), YC);
  return o;
}
__device__ __forceinline__ float4 decode_side(const float* __restrict__ reg,
                                              const float4* __restrict__ props,
                                              int grow, int ci, int isR) {
  const float4 rr = *(const float4*)(reg + (size_t)grow * REGW + ci * 8 + isR * 4);
  return decode_math(rr, props[grow]);
}

// ---------------------------------------------------------------------------
// K1: wide per-row softmax-argmax -> v32 + ci16; first 72 blocks also zero out;
// block 0 resets the cross-block handshake flags (re-poison safety).
// ---------------------------------------------------------------------------
__global__ __launch_bounds__(256) void score_kernel(
    const float* __restrict__ logits,
    unsigned* __restrict__ v32G, unsigned short* __restrict__ ci16G,
    int* __restrict__ doneG, float* __restrict__ out) {
  int row  = blockIdx.x * 4 + (threadIdx.x >> 6);
  int lane = threadIdx.x & 63;
  if (blockIdx.x == 0 && threadIdx.x < NIMG) doneG[threadIdx.x] = 0;
  if (blockIdx.x < 72) {                // zero output: 72*256 = 18432 float4s
    int g = blockIdx.x * 256 + threadIdx.x;
    ((float4*)out)[g] = make_float4(0.f, 0.f, 0.f, 0.f);
  }
  const float* lr = logits + (size_t)row * NCLS;
  float a = lr[lane];
  float b = (lane < NCLS - 64) ? lr[lane + 64] : -INFINITY;
  float v; int ci;
  if (b > a) { v = b; ci = lane + 64; } else { v = a; ci = lane; }
  for (int o = 32; o; o >>= 1) {        // wave argmax, min-index ties
    float ov = __shfl_xor(v, o);
    int   oc = __shfl_xor(ci, o);
    if (ov > v || (ov == v && oc < ci)) { v = ov; ci = oc; }
  }
  float e = expf(a - v) + ((lane < NCLS - 64) ? expf(b - v) : 0.0f);
  for (int o = 32; o; o >>= 1) e += __shfl_xor(e, o);
  if (lane == 0) {
    float score = 1.0f / e;             // softmax at argmax (numerator exp(0))
    unsigned vv = 0xFFFFFFFFu;
    if (ci >= 1 && score > SCORE_THRESH) {
      unsigned uu = __float_as_uint(score);
      uu = (uu & 0x80000000u) ? ~uu : (uu | 0x80000000u);
      vv = ~uu;                         // ascending vv == descending score
    }
    v32G[row]  = vv;
    ci16G[row] = (unsigned short)ci;
  }
}

// ---- phase-2 shared layout (~69 KB) ----
struct P2S {
  int hist[NBIN];              // 32 KB
  u64 keys[MAXC];              // 4 KB   key = v<<32 | p<<21 | ci<<14
  unsigned short ssort[MAXC];  // 1 KB   sorted pos -> row
  unsigned svs[MAXC];          // 2 KB   sorted pos -> v32
  float4 bx[MAXC];             // 8 KB   sorted decoded boxes
  u64 mat[TRIP];               // 20 KB  triangular bit matrix
  int rnk[MAXC];               // 2 KB   unsorted slot -> rank
  int wsum[16];
  int Ts, cnts, ovf;
};

// ---- fallback shared layout (~53 KB), overlaid on P2S ----
struct SN {
  u64 keys[NPROP];
  unsigned short sidx[NPROP];
  unsigned v32s[NPROP];
  float4 bxL[MAXC], bxR[MAXC];
  float  arL[MAXC], arR[MAXC];
  u64 keepbL[NPROP / 64], keepbR[NPROP / 64];
  u64 rowmL[64], rowmR[64];
  float4 cbL[64], cbR[64];
  float  cbLa[64], cbRa[64];
  u64 aL, aR;
  int cnt, prevCount, done, ccL, ccR, needFB;
  unsigned kthV;
};

__device__ __forceinline__ float4 get_sboxN(SN* S, const float* reg,
                                            const float4* lp4, const float4* rp4,
                                            const unsigned short* ci16G,
                                            int b, int pos, int isR) {
  if (pos < MAXC) return isR ? S->bxR[pos] : S->bxL[pos];
  int row = S->sidx[pos];
  int grow = b * NPROP + row;
  return decode_side(reg, isR ? rp4 : lp4, grow, ci16G[grow], isR);
}

// ---------------------------------------------------------------------------
// K2' (8 blocks = image x side, 1024 thr): select + decode(overlapped with
// rank-sort) + ballot-matrix + greedy; side-1 publishes keepR via agent-scope
// release; side-0 runs finale + dormant exact fallback.
// R9: sort widened to 8 waves x 1 key (2 waves/SIMD latency hiding, broadcast
// LDS reads, no atomics) — everything else verbatim from the R6-verified body.
// ---------------------------------------------------------------------------
__global__ __launch_bounds__(1024) void nms_fused_kernel(
    const unsigned* __restrict__ v32G, const unsigned short* __restrict__ ci16G,
    const float* __restrict__ reg, const float* __restrict__ lp,
    const float* __restrict__ rp,
    float4* __restrict__ bxRG, u64* __restrict__ keepRG,
    int* __restrict__ doneG, float* __restrict__ out) {
  constexpr unsigned SMEM = (sizeof(P2S) > sizeof(SN)) ? sizeof(P2S) : sizeof(SN);
  __shared__ __align__(16) char smemRaw[SMEM];
  P2S& P = *reinterpret_cast<P2S*>(smemRaw);
  SN&  S = *reinterpret_cast<SN*>(smemRaw);

  int b = blockIdx.x >> 1, side = blockIdx.x & 1;
  int tid = threadIdx.x, ln = tid & 63, w = tid >> 6;
  const unsigned* v32 = v32G + b * NPROP;
  const unsigned short* ci16 = ci16G + b * NPROP;

  // ---- select: hist threshold (loads prefetched over LDS zeroing) ----
  unsigned vA0 = v32[tid], vA1 = v32[tid + 1024];
  unsigned cA0 = ci16[tid], cA1 = ci16[tid + 1024];
  if (tid == 0) { P.Ts = NBIN - 1; P.cnts = 0; P.ovf = 0; }
  for (int i = tid; i < NBIN / 4; i += 1024)
    ((int4*)P.hist)[i] = make_int4(0, 0, 0, 0);
  __syncthreads();
  if (vA0 != 0xFFFFFFFFu) atomicAdd(&P.hist[vA0 >> 19], 1);
  if (vA1 != 0xFFFFFFFFu) atomicAdd(&P.hist[vA1 >> 19], 1);
  __syncthreads();
  {  // scan 8192 bins (8/thread) -> threshold bin Ts (cum >= SEL), total
    int base = tid * 8;
    int c[8]; int acc = 0;
#pragma unroll
    for (int k = 0; k < 8; ++k) { acc += P.hist[base + k]; c[k] = acc; }
    int tot = acc, v = tot;
#pragma unroll
    for (int o = 1; o < 64; o <<= 1) { int n = __shfl_up(v, o); if (ln >= o) v += n; }
    if (ln == 63) P.wsum[w] = v;
    __syncthreads();
    if (tid < 16) {
      int x = P.wsum[tid];
#pragma unroll
      for (int o = 1; o < 16; o <<= 1) { int n = __shfl_up(x, o); if (tid >= o) x += n; }
      P.wsum[tid] = x;
    }
    __syncthreads();
    int incl = ((w > 0) ? P.wsum[w - 1] : 0) + v;
    int off = incl - tot;
    int prev = off;
#pragma unroll
    for (int k = 0; k < 8; ++k) {
      int cur = off + c[k];
      if (cur >= SEL && prev < SEL) P.Ts = base + k;
      prev = cur;
    }
  }
  __syncthreads();
  int T = P.Ts, nvTot = P.wsum[15];
  {  // compact bin <= T (cached regs; key carries ci below p: order = (v,p))
    unsigned vv[2] = {vA0, vA1};
    unsigned cc[2] = {cA0, cA1};
#pragma unroll
    for (int it = 0; it < 2; ++it) {
      int p = tid + it * 1024;
      unsigned v = vv[it];
      bool cand = (v != 0xFFFFFFFFu) && ((int)(v >> 19) <= T);
      u64 mb = __ballot(cand);
      int lpos = (int)__popcll(mb & ((1ull << ln) - 1ull));
      int wb = 0;
      if (ln == 0 && mb) wb = atomicAdd(&P.cnts, (int)__popcll(mb));
      wb = __shfl(wb, 0);
      if (cand) {
        int dst = wb + lpos;
        if (dst < MAXC)
          P.keys[dst] = ((u64)v << 32) | ((u64)p << 21) | ((u64)cc[it] << 14);
        else P.ovf = 1;
      }
    }
  }
  __syncthreads();
  int C1 = P.cnts;
  bool skipSel = (C1 > MAXC) || P.ovf;   // block-uniform
  u64 A[WRD];                            // greedy result (wave 0 only)

  if (!skipSel) {
    // ---- decode loads issued EARLY (unsorted slot tid), overlap rank-sort ----
    float4 rrD, ppD;
    unsigned myv = 0; int myp = 0;
    bool hasKey = (tid < C1);
    if (hasKey) {
      u64 k = P.keys[tid];
      myv = (unsigned)(k >> 32);
      myp = (int)((k >> 21) & 0x7FF);
      int myci = (int)((k >> 14) & 0x7F);
      int grow = b * NPROP + myp;
      ppD = ((const float4*)(side ? rp : lp))[grow];
      rrD = *(const float4*)(reg + (size_t)grow * REGW + myci * 8 + side * 4);
    }
    // ---- rank-sort: 8 waves, 1 key/thread (2 waves/SIMD hide LDS latency;
    //      broadcast same-address reads, no atomics, direct rnk write) ----
    if (tid < 512) {
      u64 k0 = (tid < C1) ? P.keys[tid] : ~0ull;
      int r0 = 0;
#pragma unroll 4
      for (int j = 0; j < C1; ++j)
        r0 += (P.keys[j] < k0) ? 1 : 0;
      if (tid < C1) P.rnk[tid] = r0;
    }
    __syncthreads();
    // ---- decode compute + scatter to sorted position ----
    if (hasKey) {
      int R = P.rnk[tid];
      float4 B = decode_math(rrD, ppD);
      P.bx[R] = B;
      P.ssort[R] = (unsigned short)myp;
      P.svs[R] = myv;
      if (side) bxRG[b * MAXC + R] = B;   // side-1 publishes boxes for finale
    }
    if (tid >= C1 && tid < MAXC) P.bx[tid] = make_float4(0.f, 0.f, 0.f, 0.f);
    __syncthreads();

    // ---- matrix build: register-held columns + row-broadcast ballot ----
    int WRDu = (C1 + 63) >> 6;
    {
      int rb = w & 7, part = w >> 3;
      int K = WRDu - rb;
      if (K > 0 && rb * 64 < C1) {
        float4 cbx[8]; float car[8];
#pragma unroll
        for (int k = 0; k < 8; ++k) {
          if (k < K) {
            cbx[k] = P.bx[(rb + k) * 64 + ln];
            car[k] = areaf(cbx[k]);
          }
        }
        u64 rw[8];
#pragma unroll
        for (int k = 0; k < 8; ++k) rw[k] = 0ull;
        int tb = 0;
        for (int kk = 0; kk < rb; ++kk) tb += ((8 - kk) | 1);
        int Sw = (8 - rb) | 1;
        int r0 = part * 32;
        int rlim = C1 - rb * 64; if (rlim > 64) rlim = 64;  // rows >= C1 unread
        for (int j = 0; j < 32; ++j) {
          int rl = r0 + j;
          if (rl >= rlim) break;                 // uniform (rlim block-uniform)
          float4 rbx = P.bx[rb * 64 + rl];       // same-address broadcast
          float rar = areaf(rbx);
#pragma unroll
          for (int k = 0; k < 8; ++k) {
            if (k < K) {
              u64 bal = __ballot(iou_gt(rbx, rar, cbx[k], car[k]));
              if (k == 0) bal &= ~((2ull << rl) - 1ull);   // keep only col > r
              rw[k] = (ln == rl) ? bal : rw[k];
            }
          }
        }
        if (ln >= r0 && ln < r0 + 32 && ln < rlim) {
          u64* myrow = &P.mat[tb * 64 + ln * Sw];
#pragma unroll
          for (int k = 0; k < 8; ++k)
            if (k < K) myrow[k] = rw[k];
        }
      }
    }
    __syncthreads();

    // ---- greedy (verbatim): wave 0, all lanes redundant, zero barriers ----
    if (w == 0) {
#pragma unroll
      for (int t = 0; t < WRD; ++t) {
        int b0 = t * 64;
        A[t] = (C1 >= b0 + 64) ? ~0ull : (C1 > b0 ? ((1ull << (C1 - b0)) - 1ull) : 0ull);
      }
      int tbase = 0;
#pragma unroll
      for (int wb = 0; wb < WRD; ++wb) {
        if (wb * 64 < C1) {
          const int Sw = (8 - wb) | 1;
          const u64* rowp = &P.mat[tbase];
          u64 aw = A[wb];
#pragma unroll
          for (int g = 0; g < 4; ++g) {
            u64 d[16];
#pragma unroll
            for (int k = 0; k < 16; ++k) d[k] = rowp[(g * 16 + k) * Sw];
#pragma unroll
            for (int k = 0; k < 16; ++k) {
              u64 msk = 0ull - ((aw >> (g * 16 + k)) & 1ull);
              aw &= ~(msk & d[k]);
            }
          }
          A[wb] = aw;
          bool alive = (aw >> ln) & 1ull;
#pragma unroll
          for (int t = wb + 1; t < WRD; ++t) {
            if (t * 64 < C1) {
              u64 x = alive ? rowp[ln * Sw + (t - wb)] : 0ull;
#pragma unroll
              for (int o = 1; o < 64; o <<= 1)
                x |= __shfl_xor((unsigned long long)x, o);
              A[t] &= ~x;
            }
          }
        }
        tbase += 64 * ((8 - wb) | 1);
      }
      if (ln == 0 && side == 1) {        // only side-1's keeps cross blocks
        u64* kG = keepRG + b * WRD;
#pragma unroll
        for (int t = 0; t < WRD; ++t)
          if (t * 64 < C1) kG[t] = A[t];
      }
    }
  }
  __syncthreads();   // all side-1 global writes happen-before tid0's release

  // ---- cross-block handshake: side-1 releases, side-0 acquires ----
  if (side == 1) {
    if (tid == 0) {
      __threadfence();
      __hip_atomic_store(&doneG[b], 1, __ATOMIC_RELEASE, __HIP_MEMORY_SCOPE_AGENT);
    }
    return;
  }
  if (tid == 0) {
    while (__hip_atomic_load(&doneG[b], __ATOMIC_ACQUIRE,
                             __HIP_MEMORY_SCOPE_AGENT) == 0)
      __builtin_amdgcn_s_sleep(2);
    __threadfence();
  }
  __syncthreads();

  // =============== finale (wave 0 of side-0 block) ===============
  float* ob = out + (size_t)b * NPROP * 9;
  int C1e = skipSel ? 0 : C1;
  if (w == 0) {
    int before = 0;
    unsigned kth = 0;
    for (int wb = 0; wb * 64 < C1e; ++wb) {
      u64 m = A[wb] & keepRG[b * WRD + wb];
      int pos = wb * 64 + ln;
      bool bit = (m >> ln) & 1ull;
      int rank = before + (int)__popcll(m & ((1ull << ln) - 1ull));
      unsigned vv = P.svs[pos];
      u64 selm = __ballot(bit && rank == DETS - 1);
      if (selm) kth = __shfl(vv, __ffsll(selm) - 1);
      bool qual = bit && (rank < DETS || vv == kth);
      if (qual) {
        int row = P.ssort[pos];
        float4 L = P.bx[pos];              // side-0's own (left) boxes, LDS
        float4 R4 = bxRG[b * MAXC + pos];  // side-1's boxes, global
        float* orow = ob + row * 9;
        orow[0]=L.x; orow[1]=L.y; orow[2]=L.z; orow[3]=L.w;
        orow[4]=R4.x; orow[5]=R4.y; orow[6]=R4.z; orow[7]=R4.w;
        orow[8]=score_from_v(vv);
      }
      before += (int)__popcll(m);
    }
    if (ln == 0) {
      S.needFB = (before < DETS && nvTot > C1e) ? 1 : 0;
      S.cnt = 0; S.prevCount = 0; S.done = 0; S.kthV = 0u;
    }
  }
  __syncthreads();
  if (!S.needFB) return;

  // ---- exact fallback (verbatim R6 path): full compact/sort/chunk NMS ----
  const float4* lp4 = (const float4*)lp;
  const float4* rp4 = (const float4*)rp;
  float4* ob4 = (float4*)ob;
  float4 z4 = make_float4(0.f, 0.f, 0.f, 0.f);
  for (int i = tid; i < NPROP * 9 / 4; i += 1024) ob4[i] = z4;
  for (int p = tid; p < NPROP; p += 1024) {
    unsigned v = v32G[b * NPROP + p];
    S.v32s[p] = v;
    bool cand = (v != 0xFFFFFFFFu);
    u64 mb = __ballot(cand);
    int lpos = (int)__popcll(mb & ((1ull << ln) - 1ull));
    int wb = 0;
    if (ln == 0 && mb) wb = atomicAdd(&S.cnt, (int)__popcll(mb));
    wb = __shfl(wb, 0);
    if (cand) S.keys[wb + lpos] = ((u64)v << 16) | (unsigned)p;
  }
  __syncthreads();
  int C2 = S.cnt;
  int CbEnd = (C2 + 63) & ~63;
  {
    int i0 = tid, i1 = tid + 1024;
    u64 k0 = (i0 < C2) ? S.keys[i0] : ~0ull;
    u64 k1 = (i1 < C2) ? S.keys[i1] : ~0ull;
    int r0 = 0, r1 = 0;
#pragma unroll 4
    for (int j = 0; j < C2; ++j) {
      u64 kj = S.keys[j];
      r0 += (kj < k0) ? 1 : 0;
      r1 += (kj < k1) ? 1 : 0;
    }
    if (i0 < C2) S.sidx[r0] = (unsigned short)(k0 & 0xFFFFull);
    if (i1 < C2) S.sidx[r1] = (unsigned short)(k1 & 0xFFFFull);
  }
  for (int i = C2 + tid; i < CbEnd; i += 1024) S.sidx[i] = 0;
  for (int wd = tid; wd < NPROP / 64; wd += 1024) {
    int b0 = wd << 6;
    u64 mf = 0ull;
    if (C2 >= b0 + 64) mf = ~0ull;
    else if (C2 > b0)  mf = (1ull << (C2 - b0)) - 1ull;
    S.keepbL[wd] = mf; S.keepbR[wd] = mf;
  }
  __syncthreads();
  {
    int lim = min(CbEnd, MAXC);
    for (int i = tid; i < lim; i += 1024) {
      if (i < C2) {
        int row = S.sidx[i];
        int grow = b * NPROP + row;
        int ci = ci16G[grow];
        float4 L = decode_side(reg, lp4, grow, ci, 0);
        float4 R = decode_side(reg, rp4, grow, ci, 1);
        S.bxL[i] = L; S.arL[i] = areaf(L);
        S.bxR[i] = R; S.arR[i] = areaf(R);
      } else {
        S.bxL[i] = z4; S.arL[i] = 1.0f;
        S.bxR[i] = z4; S.arR[i] = 1.0f;
      }
    }
  }
  __syncthreads();
  for (int base = 0; base < CbEnd; base += 64) {
    {
      int isR = (w >= 8);
      float4 cbx = get_sboxN(&S, reg, lp4, rp4, ci16G, b, base + ln, isR);
      float car = (base + ln < MAXC) ? (isR ? S.arR[base + ln] : S.arL[base + ln])
                                     : areaf(cbx);
      int w8 = w & 7;
#pragma unroll
      for (int k = 0; k < 8; ++k) {
        int row = w8 * 8 + k;
        float4 rbx;
        rbx.x = __shfl(cbx.x, row); rbx.y = __shfl(cbx.y, row);
        rbx.z = __shfl(cbx.z, row); rbx.w = __shfl(cbx.w, row);
        float rar = __shfl(car, row);
        bool bit = (ln > row) && iou_gt(rbx, rar, cbx, car);
        u64 bal = __ballot(bit);
        if (ln == 0) { if (isR) S.rowmR[row] = bal; else S.rowmL[row] = bal; }
      }
    }
    __syncthreads();
    if (tid < 128) {
      int isR = (tid >= 64);
      u64* km = isR ? S.keepbR : S.keepbL;
      u64* rm = isR ? S.rowmR  : S.rowmL;
      u64 a = km[base >> 6];
#pragma unroll
      for (int j = 0; j < 64; ++j)
        a &= ~((0ull - ((a >> j) & 1ull)) & rm[j]);
      if (ln == 0) {
        km[base >> 6] = a;
        if (isR) { S.aR = a; S.ccR = __popcll(a); }
        else     { S.aL = a; S.ccL = __popcll(a); }
      }
      if ((a >> ln) & 1ull) {
        int pos = __popcll(a & ((1ull << ln) - 1ull));
        float4 v = get_sboxN(&S, reg, lp4, rp4, ci16G, b, base + ln, isR);
        if (isR) { S.cbR[pos] = v; S.cbRa[pos] = areaf(v); }
        else     { S.cbL[pos] = v; S.cbLa[pos] = areaf(v); }
      }
    }
    __syncthreads();
    if (w == 0) {
      u64 m = S.aL & S.aR;
      int before = S.prevCount;
      bool bit = (m >> ln) & 1ull;
      int rank = before + (int)__popcll(m & ((1ull << ln) - 1ull));
      int row = S.sidx[base + ln];
      unsigned vv = S.v32s[row];
      u64 selm = __ballot(bit && rank == DETS - 1);
      unsigned keffV = S.kthV;
      if (selm) keffV = __shfl(vv, __ffsll(selm) - 1);
      bool qual = bit && (rank < DETS || vv == keffV);
      if (qual) {
        float4 L = get_sboxN(&S, reg, lp4, rp4, ci16G, b, base + ln, 0);
        float4 R = get_sboxN(&S, reg, lp4, rp4, ci16G, b, base + ln, 1);
        float s = score_from_v(vv);
        float* orow = ob + row * 9;
        orow[0]=L.x; orow[1]=L.y; orow[2]=L.z; orow[3]=L.w;
        orow[4]=R.x; orow[5]=R.y; orow[6]=R.z; orow[7]=R.w;
        orow[8]=s;
      }
      if (ln == 0) {
        if (selm) S.kthV = keffV;
        int nc = before + (int)__popcll(m);
        S.prevCount = nc;
        if (nc >= DETS) {
          int nxt = base + 64;
          bool cont = false;
          if (nxt < C2) cont = (S.v32s[S.sidx[nxt]] == keffV);
          if (!cont) S.done = 1;
        }
      }
    } else {
      int cL = S.ccL, cR = S.ccR;
      if ((cL | cR) != 0) {
        for (int p = base + 64 + (tid - 64); p < CbEnd; p += 960) {
          float4 mbL = get_sboxN(&S, reg, lp4, rp4, ci16G, b, p, 0);
          float al = (p < MAXC) ? S.arL[p] : areaf(mbL);
          bool supL = false;
          for (int q = 0; q < cL; ++q)
            supL = supL || iou_gt(mbL, al, S.cbL[q], S.cbLa[q]);
          if (supL) atomicAnd(&S.keepbL[p >> 6], ~(1ull << (p & 63)));
          float4 mbR = get_sboxN(&S, reg, lp4, rp4, ci16G, b, p, 1);
          float ar_ = (p < MAXC) ? S.arR[p] : areaf(mbR);
          bool supR = false;
          for (int q = 0; q < cR; ++q)
            supR = supR || iou_gt(mbR, ar_, S.cbR[q], S.cbRa[q]);
          if (supR) atomicAnd(&S.keepbR[p >> 6], ~(1ull << (p & 63)));
        }
      }
    }
    __syncthreads();
    if (S.done) break;
  }
}

// ---------------------------------------------------------------------------
extern "C" void kernel_launch(void* const* d_in, const int* in_sizes, int n_in,
                              void* d_out, int out_size, void* d_ws, size_t ws_size,
                              hipStream_t stream) {
  const float* logits = (const float*)d_in[0];   // [8192, 81]
  const float* reg    = (const float*)d_in[1];   // [8192, 648]
  const float* lprop  = (const float*)d_in[2];   // [8192, 4]
  const float* rprop  = (const float*)d_in[3];   // [8192, 4]
  float* out = (float*)d_out;                    // [4, 2048, 9]

  char* ws = (char*)d_ws;
  unsigned*       v32G   = (unsigned*)(ws + 0);          // 32 KB
  unsigned short* ci16G  = (unsigned short*)(ws + 32768);// 16 KB
  float4*         bxRG   = (float4*)(ws + 49152);        // 32 KB
  u64*            keepRG = (u64*)(ws + 81920);           // 256 B
  int*            doneG  = (int*)(ws + 82176);           // 16 B

  score_kernel<<<NIMG * NPROP / 4, 256, 0, stream>>>(logits, v32G, ci16G,
                                                     doneG, out);
  nms_fused_kernel<<<2 * NIMG, 1024, 0, stream>>>(v32G, ci16G, reg, lprop, rprop,
                                                  bxRG, keepRG, doneG, out);
}